// Round 9
// baseline (74.615 us; speedup 1.0000x reference)
//
#include <hip/hip_runtime.h>

#define DSZ 128
#define NVOX 4194304.0f

__global__ void ncc_zero(float* out) { out[0] = 0.0f; }

__device__ __forceinline__ float4 f4add(const float4 a, const float4 b) {
    return make_float4(a.x + b.x, a.y + b.y, a.z + b.z, a.w + b.w);
}
__device__ __forceinline__ float4 f4sub(const float4 a, const float4 b) {
    return make_float4(a.x - b.x, a.y - b.y, a.z - b.z, a.w - b.w);
}

// Tile: 16x × 32y × 8z. 1024 blocks, 256 threads, 4 blocks/CU (grid-capped;
// LDS 29.4 KB allows 5). 2-slot double-buffer, 2 barriers/round.
__global__ __launch_bounds__(256, 4) void ncc_main(const float* __restrict__ Iin,
                                                   const float* __restrict__ Jin,
                                                   float* __restrict__ out)
{
    const int tx0 = blockIdx.x * 16;
    const int ty0 = blockIdx.y * 32;
    const int b   = blockIdx.z >> 4;
    const int tz0 = (blockIdx.z & 15) * 8;
    const int tid = threadIdx.x;
    const int lx  = tid & 15;        // Phase-B x
    const int ys  = tid >> 4;        // 0..15 -> owns columns y = 2ys, 2ys+1

    const float* __restrict__ Ib = Iin + b * (DSZ * DSZ * DSZ);
    const float* __restrict__ Jb = Jin + b * (DSZ * DSZ * DSZ);

    // Double-buffered x-summed moments, 40 halo rows (32y + 8).
    // s4m stride 17 f4 (68 words ≡ 4 mod 32: uniform bank spread across the
    // full-wave footprint); s1v stride 24 floats (2 lanes/bank = free).
    __shared__ float4 s4m[2][40][17];   // (sumI,sumJ,sumII,sumJJ)  21760 B
    __shared__ float  s1v[2][40][24];   // sumIJ                     7680 B

    // ring-of-8 z-window per column, modular compile-time slots (4-rnd unroll)
    float4 rA4[8], rB4[8];
    float  rA1[8], rB1[8];
#pragma unroll
    for (int i = 0; i < 8; ++i) {
        rA4[i] = make_float4(0.f, 0.f, 0.f, 0.f); rB4[i] = rA4[i];
        rA1[i] = 0.f; rB1[i] = 0.f;
    }
    float4 zA4 = make_float4(0.f, 0.f, 0.f, 0.f), zB4 = zA4;
    float  zA1 = 0.f, zB1 = 0.f;
    float  acc = 0.f;

    auto emit_cc = [&](const float4& z4, const float z1) {
        const float inv = 1.0f / 729.0f;
        const float uI = z4.x * inv;
        const float uJ = z4.y * inv;
        const float cross = z1 - uJ * z4.x - uI * z4.y + uI * uJ * 729.0f;
        const float Ivar  = z4.z - 2.0f * uI * z4.x + uI * uI * 729.0f;
        const float Jvar  = z4.w - 2.0f * uJ * z4.y + uJ * uJ * 729.0f;
        acc += cross * cross / (Ivar * Jvar + 1e-5f);
    };

#pragma unroll 1                       // outer loop stays rolled (spill protection)
    for (int mr = 0; mr < 2; ++mr) {
#pragma unroll
        for (int r4 = 0; r4 < 4; ++r4) {
            const int rnd = 4 * mr + r4;

            // ---- Phase A: direct-from-global x-pass. 320 tasks on 256
            //      threads (wave 0 takes a second task; wave-uniform). ----
            for (int t = tid; t < 320; t += 256) {
                const int p   = (t >= 160);
                const int t2  = t - 160 * p;
                const int r   = t2 >> 2;            // 0..39 halo row
                const int xg  = t2 & 3;             // group of 4 x-outputs
                const int zp  = tz0 + 2 * rnd + p - 4;
                const int gy  = ty0 + r - 4;
                const int gxb = tx0 + 4 * xg - 4;
                const bool ok = ((unsigned)zp < (unsigned)DSZ) &&
                                ((unsigned)gy < (unsigned)DSZ);
                const int zoff = (zp * DSZ + gy) * DSZ;

                float vi[12], vj[12];
#pragma unroll
                for (int g = 0; g < 3; ++g) {
                    const int gx = gxb + 4 * g;
                    float4 va = make_float4(0.f, 0.f, 0.f, 0.f);
                    float4 vb = va;
                    if (ok && (unsigned)gx < (unsigned)DSZ) {
                        va = *(const float4*)(Ib + zoff + gx);
                        vb = *(const float4*)(Jb + zoff + gx);
                    }
                    vi[4*g+0]=va.x; vi[4*g+1]=va.y; vi[4*g+2]=va.z; vi[4*g+3]=va.w;
                    vj[4*g+0]=vb.x; vj[4*g+1]=vb.y; vj[4*g+2]=vb.z; vj[4*g+3]=vb.w;
                }

                float wI=0.f, wJ=0.f, wII=0.f, wJJ=0.f, wIJ=0.f;
#pragma unroll
                for (int k = 0; k < 9; ++k) {
                    wI += vi[k]; wJ += vj[k];
                    wII = fmaf(vi[k], vi[k], wII);
                    wJJ = fmaf(vj[k], vj[k], wJJ);
                    wIJ = fmaf(vi[k], vj[k], wIJ);
                }
                float mIJ[4];
                s4m[p][r][4*xg] = make_float4(wI, wJ, wII, wJJ);
                mIJ[0] = wIJ;
#pragma unroll
                for (int j = 1; j < 4; ++j) {
                    const float ai = vi[8+j], aj = vj[8+j];
                    const float di = vi[j-1], dj = vj[j-1];
                    wI += ai - di; wJ += aj - dj;
                    wII += fmaf(ai, ai, -di * di);
                    wJJ += fmaf(aj, aj, -dj * dj);
                    wIJ += fmaf(ai, aj, -di * dj);
                    s4m[p][r][4*xg + j] = make_float4(wI, wJ, wII, wJJ);
                    mIJ[j] = wIJ;
                }
                *(float4*)&s1v[p][r][4*xg] = make_float4(mIJ[0], mIJ[1], mIJ[2], mIJ[3]);
            }
            __syncthreads();           // A-writes visible to B

            // ---- Phase B: y-pass (2 columns from 10 rows) + ring z ----
#pragma unroll
            for (int p = 0; p < 2; ++p) {
                float4 c4 = make_float4(0.f, 0.f, 0.f, 0.f);
                float  c1 = 0.f;
                float4 r0v; float r0s;
#pragma unroll
                for (int dy = 0; dy < 9; ++dy) {
                    const float4 t4 = s4m[p][2*ys + dy][lx];
                    const float  t1 = s1v[p][2*ys + dy][lx];
                    if (dy == 0) { r0v = t4; r0s = t1; }
                    c4 = f4add(c4, t4);
                    c1 += t1;
                }
                const float4 r9v = s4m[p][2*ys + 9][lx];
                const float  r9s = s1v[p][2*ys + 9][lx];
                const float4 d4 = f4add(f4sub(c4, r0v), r9v);   // column B sum
                const float  d1 = c1 - r0s + r9s;

                const int k = (2 * r4 + p) & 7;     // compile-time ring slot

                // column A (y = ty0 + 2*ys)
                zA4 = f4add(zA4, c4); zA1 += c1;
                if (mr > 0) emit_cc(zA4, zA1);
                zA4 = f4sub(zA4, rA4[k]); zA1 -= rA1[k];
                rA4[k] = c4; rA1[k] = c1;

                // column B (y = ty0 + 2*ys + 1)
                zB4 = f4add(zB4, d4); zB1 += d1;
                if (mr > 0) emit_cc(zB4, zB1);
                zB4 = f4sub(zB4, rB4[k]); zB1 -= rB1[k];
                rB4[k] = d4; rB1[k] = d1;
            }
            __syncthreads();           // protect slots before next round's A
        }
    }

    // block reduction: wave shuffle then cross-wave via LDS
#pragma unroll
    for (int off = 32; off > 0; off >>= 1) acc += __shfl_down(acc, off);
    __shared__ float wpart[4];
    if ((tid & 63) == 0) wpart[tid >> 6] = acc;
    __syncthreads();
    if (tid == 0) {
        const float s = wpart[0] + wpart[1] + wpart[2] + wpart[3];
        atomicAdd(out, s * (-1.0f / NVOX));
    }
}

extern "C" void kernel_launch(void* const* d_in, const int* in_sizes, int n_in,
                              void* d_out, int out_size, void* d_ws, size_t ws_size,
                              hipStream_t stream)
{
    // setup_inputs order: d_in[0] = y_pred (J), d_in[1] = y_true (I)
    const float* J = (const float*)d_in[0];
    const float* I = (const float*)d_in[1];
    float* out = (float*)d_out;

    ncc_zero<<<dim3(1), dim3(1), 0, stream>>>(out);
    dim3 grid(DSZ / 16, DSZ / 32, 2 * (DSZ / 8));  // 8 x 4 x 32 = 1024 blocks
    ncc_main<<<grid, dim3(256), 0, stream>>>(I, J, out);
}